// Round 1
// baseline (449.545 us; speedup 1.0000x reference)
//
#include <hip/hip_runtime.h>
#include <float.h>
#include <math.h>

#define NT 512
#define NWAVES (NT / 64)
#define NBINS 2048
#define CAP 2048
#define UMIN (-16.0f)
#define SEPS 1e-5f

__global__ __launch_bounds__(NT) void sampler_kernel(
    const float* __restrict__ logits,
    const float* __restrict__ temperature,
    const float* __restrict__ top_p,
    const float* __restrict__ noise_u,
    const int* __restrict__ top_k,
    float* __restrict__ out,
    int Bn, int Vn, int K)
{
  __shared__ float rv[NWAVES];
  __shared__ int   ri[NWAVES];
  __shared__ int   cnt[NBINS];
  __shared__ float mass[NBINS];
  __shared__ float cv[CAP];
  __shared__ int   ci[CAP];
  __shared__ float sv[CAP];
  __shared__ int   si[CAP];
  __shared__ float sF[8];
  __shared__ int   sI[8];

  const int b   = blockIdx.x;
  const int tid = threadIdx.x;
  const float* lrow = logits  + (size_t)b * Vn;
  const float* nrow = noise_u + (size_t)b * Vn;
  const float4* lrow4 = reinterpret_cast<const float4*>(lrow);
  const float t = temperature[b];
  const float p = top_p[b];
  const int   k = top_k[b];
  const float binw = 16.0f / NBINS;
  const float inv_binw = (float)NBINS / 16.0f;
  const int nv4 = Vn >> 2;

  // ---------------- pass 1: max + argmax (first occurrence) ----------------
  float bm = -FLT_MAX; int bi = 0x7fffffff;
  for (int i = tid; i < nv4; i += NT) {
    float4 x = lrow4[i];
    int base = i << 2;
    if (x.x > bm) { bm = x.x; bi = base; }
    if (x.y > bm) { bm = x.y; bi = base + 1; }
    if (x.z > bm) { bm = x.z; bi = base + 2; }
    if (x.w > bm) { bm = x.w; bi = base + 3; }
  }
  for (int i = (nv4 << 2) + tid; i < Vn; i += NT) {
    float x = lrow[i];
    if (x > bm) { bm = x; bi = i; }
  }
  for (int off = 32; off; off >>= 1) {
    float ov = __shfl_down(bm, off);
    int   oi = __shfl_down(bi, off);
    if (ov > bm || (ov == bm && oi < bi)) { bm = ov; bi = oi; }
  }
  if ((tid & 63) == 0) { rv[tid >> 6] = bm; ri[tid >> 6] = bi; }
  __syncthreads();
  if (tid == 0) {
    for (int w = 1; w < NWAVES; w++)
      if (rv[w] > bm || (rv[w] == bm && ri[w] < bi)) { bm = rv[w]; bi = ri[w]; }
    sF[0] = bm; sI[0] = bi;
  }
  __syncthreads();
  const float M = sF[0];
  const int gidx = sI[0];

  // ------- pass 2: sum(exp(l-M)) + count hist (+ mass hist if needed) ------
  for (int i = tid; i < NBINS; i += NT) { cnt[i] = 0; mass[i] = 0.0f; }
  __syncthreads();
  const bool needMass = (k <= 0) && (t >= SEPS);
  const float Ms = (t >= SEPS) ? (M / t) : 0.0f;
  float sloc = 0.0f;
  for (int i = tid; i < nv4; i += NT) {
    float4 xv = lrow4[i];
    float xs[4] = {xv.x, xv.y, xv.z, xv.w};
    #pragma unroll
    for (int q = 0; q < 4; q++) {
      float x = xs[q];
      float u = x - M;
      sloc += expf(u);
      int bin = (int)floorf((u - UMIN) * inv_binw);
      bin = bin < 0 ? 0 : (bin > NBINS - 1 ? NBINS - 1 : bin);
      atomicAdd(&cnt[bin], 1);
      if (needMass) atomicAdd(&mass[bin], expf(x / t - Ms));
    }
  }
  for (int i = (nv4 << 2) + tid; i < Vn; i += NT) {
    float x = lrow[i];
    float u = x - M;
    sloc += expf(u);
    int bin = (int)floorf((u - UMIN) * inv_binw);
    bin = bin < 0 ? 0 : (bin > NBINS - 1 ? NBINS - 1 : bin);
    atomicAdd(&cnt[bin], 1);
    if (needMass) atomicAdd(&mass[bin], expf(x / t - Ms));
  }
  __syncthreads();
  for (int off = 32; off; off >>= 1) sloc += __shfl_down(sloc, off);
  if ((tid & 63) == 0) rv[tid >> 6] = sloc;
  __syncthreads();
  if (tid == 0) {
    float s = 0.0f;
    for (int w = 0; w < NWAVES; w++) s += rv[w];
    sF[1] = logf(s);
  }
  __syncthreads();
  const float logZ = sF[1];

  // ---------- candidate threshold from count hist, collect, sort -----------
  if (tid == 0) {
    int cum = 0; int bsel = 0;
    for (int j = NBINS - 1; j >= 0; j--) {
      cum += cnt[j];
      if (cum >= 128) { bsel = j; break; }
    }
    sF[2] = UMIN + bsel * binw;   // lower edge of selected bin
    sI[1] = 0;
  }
  __syncthreads();
  const float edge = sF[2];
  for (int i = tid; i < nv4; i += NT) {
    float4 xv = lrow4[i];
    float xs[4] = {xv.x, xv.y, xv.z, xv.w};
    int base = i << 2;
    #pragma unroll
    for (int q = 0; q < 4; q++) {
      float u = xs[q] - M;
      if (u >= edge) {
        int pos = atomicAdd(&sI[1], 1);
        if (pos < CAP) { cv[pos] = xs[q]; ci[pos] = base + q; }
      }
    }
  }
  for (int i = (nv4 << 2) + tid; i < Vn; i += NT) {
    float u = lrow[i] - M;
    if (u >= edge) {
      int pos = atomicAdd(&sI[1], 1);
      if (pos < CAP) { cv[pos] = lrow[i]; ci[pos] = i; }
    }
  }
  __syncthreads();
  int n = sI[1]; if (n > CAP) n = CAP;
  for (int c = tid; c < n; c += NT) {
    float v = cv[c]; int id = ci[c]; int r = 0;
    for (int j = 0; j < n; j++) {
      float w = cv[j];
      r += (w > v) || (w == v && ci[j] < id);
    }
    sv[r] = v; si[r] = id;
  }
  __syncthreads();

  // ---------------- top-K logprob outputs (columns 1..K) -------------------
  float* out_ids  = out;
  float* out_idx  = out + Bn;
  float* out_lp   = out + Bn + (size_t)Bn * (K + 1);
  float* out_rank = out + Bn + (size_t)2 * Bn * (K + 1);
  for (int j = tid; j < K && j < n; j += NT) {
    out_idx[(size_t)b * (K + 1) + 1 + j] = (float)si[j];
    out_lp [(size_t)b * (K + 1) + 1 + j] = (sv[j] - M) - logZ;
  }

  // ------------------------------- sampling --------------------------------
  int sampled;
  if (t < SEPS) {
    sampled = gidx;
  } else {
    int keff = (k <= 0) ? Vn : k;
    int rand_s = 0;
    if (keff <= 99) {
      if (keff > n) keff = n;  // safety (never hits with this data)
      float* ev = mass;        // reuse (unused in this path)
      for (int j = tid; j < keff; j += NT) ev[j] = expf(sv[j] / t - Ms);
      __syncthreads();
      if (tid == 0) {
        float Z = 0.0f;
        for (int j = 0; j < keff; j++) Z += ev[j];
        float W = p * Z;
        float cum = 0.0f; int m = 0;
        for (int j = 0; j < keff; j++) {
          if (cum < W) m++; else break;
          cum += ev[j];
        }
        sI[2] = m;
      }
      __syncthreads();
      int m = sI[2];
      float key = -FLT_MAX; int kid = 0x7fffffff;
      for (int j = tid; j < m; j += NT) {
        float g = -logf(-logf(nrow[si[j]]));
        float kk = sv[j] / t + g;
        if (kk > key || (kk == key && si[j] < kid)) { key = kk; kid = si[j]; }
      }
      for (int off = 32; off; off >>= 1) {
        float ov = __shfl_down(key, off);
        int   oi = __shfl_down(kid, off);
        if (ov > key || (ov == key && oi < kid)) { key = ov; kid = oi; }
      }
      if ((tid & 63) == 0) { rv[tid >> 6] = key; ri[tid >> 6] = kid; }
      __syncthreads();
      if (tid == 0) {
        for (int w = 1; w < NWAVES; w++)
          if (rv[w] > key || (rv[w] == key && ri[w] < kid)) { key = rv[w]; kid = ri[w]; }
        sI[3] = (kid == 0x7fffffff) ? 0 : kid;
      }
      __syncthreads();
      rand_s = sI[3];
    } else {
      // fallback: top_k disabled -> full-vocab top-p via mass histogram
      if (tid == 0) {
        float Z = 0.0f;
        for (int j = 0; j < NBINS; j++) Z += mass[j];
        float W = p * Z;
        float ca = 0.0f; int Bb = 0;
        for (int j = NBINS - 1; j >= 0; j--) {
          if (ca + mass[j] >= W || j == 0) { Bb = j; break; }
          ca += mass[j];
        }
        sF[3] = W; sF[4] = ca; sI[2] = Bb; sI[1] = 0;
      }
      __syncthreads();
      const float W = sF[3]; const float CAv = sF[4]; const int Bb = sI[2];
      for (int i = tid; i < Vn; i += NT) {
        float u = lrow[i] - M;
        int bin = (int)floorf((u - UMIN) * inv_binw);
        bin = bin < 0 ? 0 : (bin > NBINS - 1 ? NBINS - 1 : bin);
        if (bin == Bb) {
          int pos = atomicAdd(&sI[1], 1);
          if (pos < CAP) { cv[pos] = lrow[i]; ci[pos] = i; }
        }
      }
      __syncthreads();
      int n2 = sI[1]; if (n2 > CAP) n2 = CAP;
      for (int c = tid; c < n2; c += NT) {
        float v = cv[c]; int id = ci[c]; int r = 0;
        for (int j = 0; j < n2; j++) {
          float w = cv[j];
          r += (w > v) || (w == v && ci[j] < id);
        }
        sv[r] = v; si[r] = id;
      }
      __syncthreads();
      float* ev = mass;  // mass fully consumed above; safe to reuse
      for (int j = tid; j < n2; j += NT) ev[j] = expf(sv[j] / t - Ms);
      __syncthreads();
      if (tid == 0) {
        float cum = CAv; int last = -1;
        for (int j = 0; j < n2; j++) {
          if (cum < W) last = j; else break;
          cum += ev[j];
        }
        sF[5] = (last >= 0) ? (sv[last] - M) : (UMIN + (Bb + 1) * binw);
      }
      __syncthreads();
      const float thr_u = sF[5];
      float key = -FLT_MAX; int kid = 0x7fffffff;
      for (int i = tid; i < Vn; i += NT) {
        float u = lrow[i] - M;
        if (u >= thr_u) {
          float g = -logf(-logf(nrow[i]));
          float kk = lrow[i] / t + g;
          if (kk > key || (kk == key && i < kid)) { key = kk; kid = i; }
        }
      }
      for (int off = 32; off; off >>= 1) {
        float ov = __shfl_down(key, off);
        int   oi = __shfl_down(kid, off);
        if (ov > key || (ov == key && oi < kid)) { key = ov; kid = oi; }
      }
      if ((tid & 63) == 0) { rv[tid >> 6] = key; ri[tid >> 6] = kid; }
      __syncthreads();
      if (tid == 0) {
        for (int w = 1; w < NWAVES; w++)
          if (rv[w] > key || (rv[w] == key && ri[w] < kid)) { key = rv[w]; kid = ri[w]; }
        sI[3] = (kid == 0x7fffffff) ? 0 : kid;
      }
      __syncthreads();
      rand_s = sI[3];
    }
    sampled = rand_s;
  }

  // ---------------------- token logprob + rank + writes --------------------
  if (tid == 0) sF[6] = lrow[sampled];
  __syncthreads();
  const float token_lp = (sF[6] - M) - logZ;
  int rloc = 0;
  for (int i = tid; i < nv4; i += NT) {
    float4 xv = lrow4[i];
    float xs[4] = {xv.x, xv.y, xv.z, xv.w};
    #pragma unroll
    for (int q = 0; q < 4; q++) {
      float lp = (xs[q] - M) - logZ;
      rloc += (lp >= token_lp) ? 1 : 0;
    }
  }
  for (int i = (nv4 << 2) + tid; i < Vn; i += NT) {
    float lp = (lrow[i] - M) - logZ;
    rloc += (lp >= token_lp) ? 1 : 0;
  }
  for (int off = 32; off; off >>= 1) rloc += __shfl_down(rloc, off);
  if ((tid & 63) == 0) ri[tid >> 6] = rloc;
  __syncthreads();
  if (tid == 0) {
    int rank = 0;
    for (int w = 0; w < NWAVES; w++) rank += ri[w];
    out_ids[b] = (float)sampled;
    out_idx[(size_t)b * (K + 1)] = (float)sampled;
    out_lp [(size_t)b * (K + 1)] = token_lp;
    out_rank[b] = (float)rank;
  }
}

extern "C" void kernel_launch(void* const* d_in, const int* in_sizes, int n_in,
                              void* d_out, int out_size, void* d_ws, size_t ws_size,
                              hipStream_t stream) {
  const float* logits = (const float*)d_in[0];
  const float* temp   = (const float*)d_in[1];
  const float* topp   = (const float*)d_in[2];
  const float* noise  = (const float*)d_in[3];
  const int*   topk   = (const int*)d_in[4];
  int Bn = in_sizes[1];            // 128
  int Vn = in_sizes[0] / Bn;       // 128256
  int Kp1 = (out_size - 2 * Bn) / (2 * Bn);  // K+1 = 21
  int K = Kp1 - 1;
  sampler_kernel<<<Bn, NT, 0, stream>>>(logits, temp, topp, noise, topk,
                                        (float*)d_out, Bn, Vn, K);
}

// Round 2
// 164.774 us; speedup vs baseline: 2.7283x; 2.7283x over previous
//
#include <hip/hip_runtime.h>
#include <float.h>
#include <math.h>

#define NT 256
#define NW (NT / 64)
#define S 16
#define NB 2048
#define CAP1 1024
#define CAP2 2048
#define TGT 128
#define XMIN (-8.0f)
#define XRANGE 16.0f
#define BINW (XRANGE / NB)
#define INVW ((float)NB / XRANGE)
#define SEPS 1e-5f

__device__ __forceinline__ int binOf(float x) {
  int bn = (int)floorf((x - XMIN) * INVW);
  return bn < 0 ? 0 : (bn > NB - 1 ? NB - 1 : bn);
}

// ---------------- K1: slice max/argmax, sumexp(local), count hist ----------
__global__ __launch_bounds__(NT) void k1(const float* __restrict__ logits,
    int V, int CS, int* __restrict__ hist, float* __restrict__ sMax,
    int* __restrict__ sArg, float* __restrict__ sSum)
{
  const int s = blockIdx.x, b = blockIdx.y, tid = threadIdx.x;
  const float* lrow = logits + (size_t)b * V;
  const int lo = s * CS, hi = min(V, lo + CS);
  __shared__ int lc[NB];
  __shared__ float wv[NW]; __shared__ int wi[NW];
  __shared__ float shM;
  for (int j = tid; j < NB; j += NT) lc[j] = 0;
  __syncthreads();

  float bm = -FLT_MAX; int bi = 0x7fffffff;
  const int vecEnd = lo + ((hi - lo) & ~3);
  const float4* l4 = reinterpret_cast<const float4*>(lrow);
  for (int i4 = (lo >> 2) + tid; i4 < (vecEnd >> 2); i4 += NT) {
    float4 x = l4[i4];
    int base = i4 << 2;
    if (x.x > bm) { bm = x.x; bi = base; }
    if (x.y > bm) { bm = x.y; bi = base + 1; }
    if (x.z > bm) { bm = x.z; bi = base + 2; }
    if (x.w > bm) { bm = x.w; bi = base + 3; }
    atomicAdd(&lc[binOf(x.x)], 1);
    atomicAdd(&lc[binOf(x.y)], 1);
    atomicAdd(&lc[binOf(x.z)], 1);
    atomicAdd(&lc[binOf(x.w)], 1);
  }
  for (int i = vecEnd + tid; i < hi; i += NT) {
    float x = lrow[i];
    if (x > bm) { bm = x; bi = i; }
    atomicAdd(&lc[binOf(x)], 1);
  }
  for (int off = 32; off; off >>= 1) {
    float ov = __shfl_down(bm, off);
    int   oi = __shfl_down(bi, off);
    if (ov > bm || (ov == bm && oi < bi)) { bm = ov; bi = oi; }
  }
  if ((tid & 63) == 0) { wv[tid >> 6] = bm; wi[tid >> 6] = bi; }
  __syncthreads();
  if (tid == 0) {
    for (int w = 1; w < NW; w++)
      if (wv[w] > bm || (wv[w] == bm && wi[w] < bi)) { bm = wv[w]; bi = wi[w]; }
    sMax[b * S + s] = bm; sArg[b * S + s] = bi; shM = bm;
  }
  __syncthreads();
  const float Ml = shM;
  float sum = 0.0f;
  for (int i4 = (lo >> 2) + tid; i4 < (vecEnd >> 2); i4 += NT) {
    float4 x = l4[i4];
    sum += expf(x.x - Ml) + expf(x.y - Ml) + expf(x.z - Ml) + expf(x.w - Ml);
  }
  for (int i = vecEnd + tid; i < hi; i += NT) sum += expf(lrow[i] - Ml);
  for (int off = 32; off; off >>= 1) sum += __shfl_down(sum, off);
  if ((tid & 63) == 0) wv[tid >> 6] = sum;
  __syncthreads();
  if (tid == 0) {
    float ts = 0.0f;
    for (int w = 0; w < NW; w++) ts += wv[w];
    sSum[b * S + s] = ts;
  }
  __syncthreads();
  for (int j = tid; j < NB; j += NT) {
    int v = lc[j];
    if (v) atomicAdd(&hist[b * NB + j], v);
  }
}

// -------- K2: combine slices -> M, gidx, logZ; hist scan -> edge; mode -----
__global__ __launch_bounds__(NT) void k2(const float* __restrict__ temp,
    const float* __restrict__ topp, const int* __restrict__ topk,
    const int* __restrict__ hist, const float* __restrict__ sMax,
    const int* __restrict__ sArg, const float* __restrict__ sSum,
    float* __restrict__ rowF, int* __restrict__ rowI)
{
  const int b = blockIdx.x, tid = threadIdx.x;
  __shared__ int lc[NB];
  __shared__ int csum[NT];
  __shared__ float shM;
  for (int j = tid; j < NB; j += NT) lc[j] = hist[b * NB + j];
  __syncthreads();
  int c0 = 0;
  for (int j = tid * (NB / NT); j < (tid + 1) * (NB / NT); j++) c0 += lc[j];
  csum[tid] = c0;
  __syncthreads();
  if (tid == 0) {
    float M = -FLT_MAX; int gi = 0x7fffffff;
    for (int s2 = 0; s2 < S; s2++) {
      float v = sMax[b * S + s2]; int ii = sArg[b * S + s2];
      if (v > M || (v == M && ii < gi)) { M = v; gi = ii; }
    }
    float Z = 0.0f;
    for (int s2 = 0; s2 < S; s2++) Z += sSum[b * S + s2] * expf(sMax[b * S + s2] - M);
    float logZ = logf(Z);
    // descending scan for edge with cum count >= TGT
    const int CH = NB / NT;
    int cum = 0; int c = NT - 1;
    for (; c >= 0; c--) {
      if (cum + csum[c] >= TGT) break;
      cum += csum[c];
    }
    if (c < 0) c = 0;
    int bsel = 0, found = -1;
    for (int j = c * CH + CH - 1; j >= c * CH; j--) {
      cum += lc[j];
      if (cum >= TGT) { found = j; break; }
    }
    bsel = (found >= 0) ? found : 0;
    float t = temp[b]; float p = topp[b]; int k = topk[b];
    int mode = (t < SEPS) ? 0 : ((k >= 1) ? 1 : 2);
    rowF[b * 16 + 0] = M;
    rowF[b * 16 + 1] = logZ;
    rowF[b * 16 + 2] = XMIN + bsel * BINW;
    rowF[b * 16 + 3] = (t >= SEPS) ? (M / t) : 0.0f;
    rowF[b * 16 + 4] = t;
    rowF[b * 16 + 5] = p;
    rowI[b * 16 + 0] = gi;
    rowI[b * 16 + 1] = mode;
    rowI[b * 16 + 2] = k;
    shM = M;
  }
  __syncthreads();
}

// -------- K3: collect candidates >= edge; mass hist for mode==2 rows -------
__global__ __launch_bounds__(NT) void k3(const float* __restrict__ logits,
    int V, int CS, const float* __restrict__ rowF, const int* __restrict__ rowI,
    float* __restrict__ mass, float* __restrict__ candV, int* __restrict__ candI,
    int* __restrict__ cnt1)
{
  const int s = blockIdx.x, b = blockIdx.y, tid = threadIdx.x;
  const float M = rowF[b * 16 + 0];
  const float edgeX = rowF[b * 16 + 2];
  const float Ms = rowF[b * 16 + 3];
  const float t = rowF[b * 16 + 4];
  const int mode = rowI[b * 16 + 1];
  const bool needMass = (mode == 2);
  (void)M;
  const float* lrow = logits + (size_t)b * V;
  const int lo = s * CS, hi = min(V, lo + CS);
  __shared__ float lm[NB];
  if (needMass) {
    for (int j = tid; j < NB; j += NT) lm[j] = 0.0f;
    __syncthreads();
  }
  const int vecEnd = lo + ((hi - lo) & ~3);
  const float4* l4 = reinterpret_cast<const float4*>(lrow);
  for (int i4 = (lo >> 2) + tid; i4 < (vecEnd >> 2); i4 += NT) {
    float4 xv = l4[i4];
    float xs[4] = {xv.x, xv.y, xv.z, xv.w};
    int base = i4 << 2;
    #pragma unroll
    for (int q = 0; q < 4; q++) {
      float x = xs[q];
      if (x >= edgeX) {
        int pos = atomicAdd(&cnt1[b], 1);
        if (pos < CAP1) { candV[b * CAP1 + pos] = x; candI[b * CAP1 + pos] = base + q; }
      }
      if (needMass) atomicAdd(&lm[binOf(x)], expf(x / t - Ms));
    }
  }
  for (int i = vecEnd + tid; i < hi; i += NT) {
    float x = lrow[i];
    if (x >= edgeX) {
      int pos = atomicAdd(&cnt1[b], 1);
      if (pos < CAP1) { candV[b * CAP1 + pos] = x; candI[b * CAP1 + pos] = i; }
    }
    if (needMass) atomicAdd(&lm[binOf(x)], expf(x / t - Ms));
  }
  if (needMass) {
    __syncthreads();
    for (int j = tid; j < NB; j += NT)
      if (lm[j] != 0.0f) atomicAdd(&mass[b * NB + j], lm[j]);
  }
}

// ---- K4: sort candidates, top-K outputs, k-path sampling, mass scan -------
__global__ __launch_bounds__(NT) void k4(const float* __restrict__ noise,
    int V, int K, const float* __restrict__ candV, const int* __restrict__ candI,
    const int* __restrict__ cnt1, const float* __restrict__ mass,
    float* __restrict__ rowF, int* __restrict__ rowI, float* __restrict__ out, int Bn)
{
  const int b = blockIdx.x, tid = threadIdx.x;
  __shared__ float cv[CAP1]; __shared__ int ci[CAP1];
  __shared__ float sv[CAP1]; __shared__ int si[CAP1];
  __shared__ float ev[CAP1];
  __shared__ float lmass[NB];
  __shared__ float fsum[NT];
  __shared__ float wv[NW]; __shared__ int wi[NW];
  __shared__ int shm;
  int n = min(cnt1[b], CAP1);
  const float M = rowF[b * 16 + 0];
  const float logZ = rowF[b * 16 + 1];
  const float Ms = rowF[b * 16 + 3];
  const float t = rowF[b * 16 + 4];
  const float p = rowF[b * 16 + 5];
  const int mode = rowI[b * 16 + 1];
  const int k = rowI[b * 16 + 2];
  const int gidx = rowI[b * 16 + 0];

  for (int j = tid; j < n; j += NT) { cv[j] = candV[b * CAP1 + j]; ci[j] = candI[b * CAP1 + j]; }
  __syncthreads();
  for (int c = tid; c < n; c += NT) {
    float v = cv[c]; int id = ci[c]; int r = 0;
    for (int j = 0; j < n; j++) {
      float w = cv[j];
      r += (w > v) || (w == v && ci[j] < id);
    }
    sv[r] = v; si[r] = id;
  }
  __syncthreads();
  float* out_idx = out + Bn;
  float* out_lp  = out + Bn + (size_t)Bn * (K + 1);
  for (int j = tid; j < K && j < n; j += NT) {
    out_idx[(size_t)b * (K + 1) + 1 + j] = (float)si[j];
    out_lp [(size_t)b * (K + 1) + 1 + j] = (sv[j] - M) - logZ;
  }
  if (mode == 0) {
    if (tid == 0) rowI[b * 16 + 4] = gidx;
  } else if (mode == 1) {
    int keff = min(k, n);
    for (int j = tid; j < keff; j += NT) ev[j] = expf(sv[j] / t - Ms);
    __syncthreads();
    if (tid == 0) {
      float Z = 0.0f;
      for (int j = 0; j < keff; j++) Z += ev[j];
      float W = p * Z;
      float cum = 0.0f; int m = 0;
      for (int j = 0; j < keff; j++) {
        if (cum < W) m++; else break;
        cum += ev[j];
      }
      shm = m;
    }
    __syncthreads();
    int m = shm;
    float key = -FLT_MAX; int kid = 0x7fffffff;
    for (int j = tid; j < m; j += NT) {
      float u = noise[(size_t)b * V + si[j]];
      float g = -logf(-logf(u));
      float kk = sv[j] / t + g;
      if (kk > key || (kk == key && si[j] < kid)) { key = kk; kid = si[j]; }
    }
    for (int off = 32; off; off >>= 1) {
      float ov = __shfl_down(key, off);
      int   oi = __shfl_down(kid, off);
      if (ov > key || (ov == key && oi < kid)) { key = ov; kid = oi; }
    }
    if ((tid & 63) == 0) { wv[tid >> 6] = key; wi[tid >> 6] = kid; }
    __syncthreads();
    if (tid == 0) {
      for (int w = 1; w < NW; w++)
        if (wv[w] > key || (wv[w] == key && wi[w] < kid)) { key = wv[w]; kid = wi[w]; }
      rowI[b * 16 + 4] = (kid == 0x7fffffff) ? 0 : kid;
    }
  } else {
    for (int j = tid; j < NB; j += NT) lmass[j] = mass[b * NB + j];
    __syncthreads();
    const int CH = NB / NT;
    float cs = 0.0f;
    for (int j = tid * CH; j < (tid + 1) * CH; j++) cs += lmass[j];
    fsum[tid] = cs;
    __syncthreads();
    if (tid == 0) {
      float Z2 = 0.0f;
      for (int c = 0; c < NT; c++) Z2 += fsum[c];
      float W = p * Z2;
      float ca = 0.0f;
      int c = NT - 1;
      for (; c >= 0; c--) {
        if (ca + fsum[c] >= W) break;
        ca += fsum[c];
      }
      if (c < 0) c = 0;
      int Bb = c * CH, found = -1;
      for (int j = c * CH + CH - 1; j >= c * CH; j--) {
        if (ca + lmass[j] >= W) { found = j; break; }
        ca += lmass[j];
      }
      if (found >= 0) Bb = found;
      rowF[b * 16 + 6] = W;
      rowF[b * 16 + 7] = ca;
      rowI[b * 16 + 3] = Bb;
    }
  }
}

// ---------------- K5: collect boundary-bin elements (mode==2) --------------
__global__ __launch_bounds__(NT) void k5(const float* __restrict__ logits,
    int V, int CS, const int* __restrict__ rowI, float* __restrict__ l2V,
    int* __restrict__ l2I, int* __restrict__ cnt2)
{
  const int s = blockIdx.x, b = blockIdx.y, tid = threadIdx.x;
  if (rowI[b * 16 + 1] != 2) return;
  const int Bb = rowI[b * 16 + 3];
  const float* lrow = logits + (size_t)b * V;
  const int lo = s * CS, hi = min(V, lo + CS);
  for (int i = lo + tid; i < hi; i += NT) {
    float x = lrow[i];
    if (binOf(x) == Bb) {
      int pos = atomicAdd(&cnt2[b], 1);
      if (pos < CAP2) { l2V[b * CAP2 + pos] = x; l2I[b * CAP2 + pos] = i; }
    }
  }
}

// --------- K6: sort boundary bin, exact prefix -> raw threshold ------------
__global__ __launch_bounds__(NT) void k6(float* __restrict__ rowF,
    const int* __restrict__ rowI, const float* __restrict__ l2V,
    const int* __restrict__ l2I, const int* __restrict__ cnt2)
{
  const int b = blockIdx.x, tid = threadIdx.x;
  if (rowI[b * 16 + 1] != 2) return;
  __shared__ float cv[CAP2]; __shared__ int ci[CAP2];
  __shared__ float sv[CAP2];
  __shared__ float ev[CAP2];
  int n2 = min(cnt2[b], CAP2);
  const float Ms = rowF[b * 16 + 3];
  const float t = rowF[b * 16 + 4];
  const float W = rowF[b * 16 + 6];
  const float CAv = rowF[b * 16 + 7];
  const int Bb = rowI[b * 16 + 3];
  for (int j = tid; j < n2; j += NT) { cv[j] = l2V[b * CAP2 + j]; ci[j] = l2I[b * CAP2 + j]; }
  __syncthreads();
  for (int c = tid; c < n2; c += NT) {
    float v = cv[c]; int id = ci[c]; int r = 0;
    for (int j = 0; j < n2; j++) {
      float w = cv[j];
      r += (w > v) || (w == v && ci[j] < id);
    }
    sv[r] = v;
  }
  __syncthreads();
  for (int j = tid; j < n2; j += NT) ev[j] = expf(sv[j] / t - Ms);
  __syncthreads();
  if (tid == 0) {
    float cum = CAv; int last = -1;
    for (int j = 0; j < n2; j++) {
      if (cum < W) last = j; else break;
      cum += ev[j];
    }
    rowF[b * 16 + 8] = (last >= 0) ? sv[last] : (XMIN + (Bb + 1) * BINW);
  }
}

// ------------- K7: sliced Gumbel-argmax over kept set (mode==2) ------------
__global__ __launch_bounds__(NT) void k7(const float* __restrict__ logits,
    const float* __restrict__ noise, int V, int CS,
    const float* __restrict__ rowF, const int* __restrict__ rowI,
    float* __restrict__ gbK, int* __restrict__ gbI)
{
  const int s = blockIdx.x, b = blockIdx.y, tid = threadIdx.x;
  if (rowI[b * 16 + 1] != 2) return;
  const float thrX = rowF[b * 16 + 8];
  const float t = rowF[b * 16 + 4];
  const float* lrow = logits + (size_t)b * V;
  const float* nrow = noise + (size_t)b * V;
  const int lo = s * CS, hi = min(V, lo + CS);
  __shared__ float wv[NW]; __shared__ int wi[NW];
  float key = -FLT_MAX; int kid = 0x7fffffff;
  for (int i = lo + tid; i < hi; i += NT) {
    float x = lrow[i];
    if (x >= thrX) {
      float g = -logf(-logf(nrow[i]));
      float kk = x / t + g;
      if (kk > key || (kk == key && i < kid)) { key = kk; kid = i; }
    }
  }
  for (int off = 32; off; off >>= 1) {
    float ov = __shfl_down(key, off);
    int   oi = __shfl_down(kid, off);
    if (ov > key || (ov == key && oi < kid)) { key = ov; kid = oi; }
  }
  if ((tid & 63) == 0) { wv[tid >> 6] = key; wi[tid >> 6] = kid; }
  __syncthreads();
  if (tid == 0) {
    for (int w = 1; w < NW; w++)
      if (wv[w] > key || (wv[w] == key && wi[w] < kid)) { key = wv[w]; kid = wi[w]; }
    gbK[b * S + s] = key; gbI[b * S + s] = kid;
  }
}

// -------- K8: finalize sampled, token_lp, first-column outputs -------------
__global__ __launch_bounds__(64) void k8(const float* __restrict__ logits,
    int V, int K, float* __restrict__ rowF, int* __restrict__ rowI,
    const float* __restrict__ gbK, const int* __restrict__ gbI,
    float* __restrict__ out, int Bn)
{
  const int b = blockIdx.x;
  if (threadIdx.x != 0) return;
  const int mode = rowI[b * 16 + 1];
  int smp;
  if (mode == 2) {
    float key = -FLT_MAX; int kid = 0x7fffffff;
    for (int s2 = 0; s2 < S; s2++) {
      float v = gbK[b * S + s2]; int ii = gbI[b * S + s2];
      if (v > key || (v == key && ii < kid)) { key = v; kid = ii; }
    }
    smp = (kid == 0x7fffffff) ? 0 : kid;
    rowI[b * 16 + 4] = smp;
  } else {
    smp = rowI[b * 16 + 4];
  }
  float lx = logits[(size_t)b * V + smp];
  float tlp = (lx - rowF[b * 16 + 0]) - rowF[b * 16 + 1];
  rowF[b * 16 + 9] = tlp;
  out[b] = (float)smp;
  out[Bn + (size_t)b * (K + 1)] = (float)smp;
  out[Bn + (size_t)Bn * (K + 1) + (size_t)b * (K + 1)] = tlp;
  out[Bn + 2 * (size_t)Bn * (K + 1) + b] = 0.0f;   // zero rank accumulator
}

// ------------------ K9: rank partial counts (lp space) ---------------------
__global__ __launch_bounds__(NT) void k9(const float* __restrict__ logits,
    int V, int CS, const float* __restrict__ rowF, float* __restrict__ out,
    int Bn, int K)
{
  const int s = blockIdx.x, b = blockIdx.y, tid = threadIdx.x;
  const float M = rowF[b * 16 + 0];
  const float logZ = rowF[b * 16 + 1];
  const float tlp = rowF[b * 16 + 9];
  const float* lrow = logits + (size_t)b * V;
  const int lo = s * CS, hi = min(V, lo + CS);
  __shared__ int wiv[NW];
  int rc = 0;
  const int vecEnd = lo + ((hi - lo) & ~3);
  const float4* l4 = reinterpret_cast<const float4*>(lrow);
  for (int i4 = (lo >> 2) + tid; i4 < (vecEnd >> 2); i4 += NT) {
    float4 x = l4[i4];
    rc += ((x.x - M) - logZ >= tlp);
    rc += ((x.y - M) - logZ >= tlp);
    rc += ((x.z - M) - logZ >= tlp);
    rc += ((x.w - M) - logZ >= tlp);
  }
  for (int i = vecEnd + tid; i < hi; i += NT)
    rc += ((lrow[i] - M) - logZ >= tlp);
  for (int off = 32; off; off >>= 1) rc += __shfl_down(rc, off);
  if ((tid & 63) == 0) wiv[tid >> 6] = rc;
  __syncthreads();
  if (tid == 0) {
    int tot = 0;
    for (int w = 0; w < NW; w++) tot += wiv[w];
    atomicAdd(&out[Bn + 2 * (size_t)Bn * (K + 1) + b], (float)tot);
  }
}

extern "C" void kernel_launch(void* const* d_in, const int* in_sizes, int n_in,
                              void* d_out, int out_size, void* d_ws, size_t ws_size,
                              hipStream_t stream) {
  const float* logits = (const float*)d_in[0];
  const float* temp   = (const float*)d_in[1];
  const float* topp   = (const float*)d_in[2];
  const float* noise  = (const float*)d_in[3];
  const int*   topk   = (const int*)d_in[4];
  const int Bn = in_sizes[1];                       // 128
  const int V  = in_sizes[0] / Bn;                  // 128256
  const int K  = (out_size - 2 * Bn) / (2 * Bn) - 1;  // 20
  const int CS = (((V + S - 1) / S) + 3) & ~3;      // slice size, mult of 4

  char* w = (char*)d_ws;
  int*   hist  = (int*)w;    w += (size_t)Bn * NB * 4;
  float* mass  = (float*)w;  w += (size_t)Bn * NB * 4;
  int*   cnt1  = (int*)w;    w += (size_t)Bn * 4;
  int*   cnt2  = (int*)w;    w += (size_t)Bn * 4;
  size_t zeroBytes = (size_t)(w - (char*)d_ws);
  float* sMax  = (float*)w;  w += (size_t)Bn * S * 4;
  int*   sArg  = (int*)w;    w += (size_t)Bn * S * 4;
  float* sSum  = (float*)w;  w += (size_t)Bn * S * 4;
  float* gbK   = (float*)w;  w += (size_t)Bn * S * 4;
  int*   gbI   = (int*)w;    w += (size_t)Bn * S * 4;
  float* candV = (float*)w;  w += (size_t)Bn * CAP1 * 4;
  int*   candI = (int*)w;    w += (size_t)Bn * CAP1 * 4;
  float* l2V   = (float*)w;  w += (size_t)Bn * CAP2 * 4;
  int*   l2I   = (int*)w;    w += (size_t)Bn * CAP2 * 4;
  float* rowF  = (float*)w;  w += (size_t)Bn * 16 * 4;
  int*   rowI  = (int*)w;    w += (size_t)Bn * 16 * 4;

  hipMemsetAsync(d_ws, 0, zeroBytes, stream);

  dim3 gs(S, Bn);
  k1<<<gs, NT, 0, stream>>>(logits, V, CS, hist, sMax, sArg, sSum);
  k2<<<Bn, NT, 0, stream>>>(temp, topp, topk, hist, sMax, sArg, sSum, rowF, rowI);
  k3<<<gs, NT, 0, stream>>>(logits, V, CS, rowF, rowI, mass, candV, candI, cnt1);
  k4<<<Bn, NT, 0, stream>>>(noise, V, K, candV, candI, cnt1, mass, rowF, rowI,
                            (float*)d_out, Bn);
  k5<<<gs, NT, 0, stream>>>(logits, V, CS, rowI, l2V, l2I, cnt2);
  k6<<<Bn, NT, 0, stream>>>(rowF, rowI, l2V, l2I, cnt2);
  k7<<<gs, NT, 0, stream>>>(logits, noise, V, CS, rowF, rowI, gbK, gbI);
  k8<<<Bn, 64, 0, stream>>>(logits, V, K, rowF, rowI, gbK, gbI, (float*)d_out, Bn);
  k9<<<gs, NT, 0, stream>>>(logits, V, CS, rowF, (float*)d_out, Bn, K);
}

// Round 3
// 135.110 us; speedup vs baseline: 3.3273x; 1.2196x over previous
//
#include <hip/hip_runtime.h>
#include <float.h>
#include <math.h>

#define NT 256
#define NW (NT / 64)
#define S 16
#define NB 2048
#define CAP1 1024
#define CAP2 1024
#define QCAP 512
#define TGT 128
#define XMIN (-8.0f)
#define BINW (1.0f / 128.0f)
#define INVW (128.0f)
#define SEPS 1e-5f

__device__ __forceinline__ int binOf(float x) {
  int bn = (int)floorf((x - XMIN) * INVW);
  return bn < 0 ? 0 : (bn > NB - 1 ? NB - 1 : bn);
}
__device__ __forceinline__ unsigned f2k(float f) {
  unsigned u = __float_as_uint(f);
  return (u & 0x80000000u) ? ~u : (u | 0x80000000u);
}
__device__ __forceinline__ float k2f(unsigned k) {
  return __uint_as_float((k & 0x80000000u) ? (k ^ 0x80000000u) : ~k);
}

// ---------------- K1: slice max/argmax, sumexp(local), count hist ----------
__global__ __launch_bounds__(NT) void k1(const float* __restrict__ logits,
    int V, int CS, int* __restrict__ hist, float* __restrict__ sMax,
    int* __restrict__ sArg, float* __restrict__ sSum)
{
  const int s = blockIdx.x, b = blockIdx.y, tid = threadIdx.x;
  const float* lrow = logits + (size_t)b * V;
  const int lo = s * CS, hi = min(V, lo + CS);
  __shared__ int lc[NB];
  __shared__ float wv[NW]; __shared__ int wi[NW];
  __shared__ float shM;
  for (int j = tid; j < NB; j += NT) lc[j] = 0;
  __syncthreads();

  float bm = -FLT_MAX; int bi = 0x7fffffff;
  const int vecEnd = lo + ((hi - lo) & ~3);
  const float4* l4 = reinterpret_cast<const float4*>(lrow);
  #pragma unroll 4
  for (int i4 = (lo >> 2) + tid; i4 < (vecEnd >> 2); i4 += NT) {
    float4 x = l4[i4];
    int base = i4 << 2;
    if (x.x > bm) { bm = x.x; bi = base; }
    if (x.y > bm) { bm = x.y; bi = base + 1; }
    if (x.z > bm) { bm = x.z; bi = base + 2; }
    if (x.w > bm) { bm = x.w; bi = base + 3; }
    atomicAdd(&lc[binOf(x.x)], 1);
    atomicAdd(&lc[binOf(x.y)], 1);
    atomicAdd(&lc[binOf(x.z)], 1);
    atomicAdd(&lc[binOf(x.w)], 1);
  }
  for (int i = vecEnd + tid; i < hi; i += NT) {
    float x = lrow[i];
    if (x > bm) { bm = x; bi = i; }
    atomicAdd(&lc[binOf(x)], 1);
  }
  for (int off = 32; off; off >>= 1) {
    float ov = __shfl_down(bm, off);
    int   oi = __shfl_down(bi, off);
    if (ov > bm || (ov == bm && oi < bi)) { bm = ov; bi = oi; }
  }
  if ((tid & 63) == 0) { wv[tid >> 6] = bm; wi[tid >> 6] = bi; }
  __syncthreads();
  if (tid == 0) {
    for (int w = 1; w < NW; w++)
      if (wv[w] > bm || (wv[w] == bm && wi[w] < bi)) { bm = wv[w]; bi = wi[w]; }
    sMax[b * S + s] = bm; sArg[b * S + s] = bi; shM = bm;
  }
  __syncthreads();
  const float Ml = shM;
  float sum = 0.0f;
  #pragma unroll 4
  for (int i4 = (lo >> 2) + tid; i4 < (vecEnd >> 2); i4 += NT) {
    float4 x = l4[i4];
    sum += expf(x.x - Ml) + expf(x.y - Ml) + expf(x.z - Ml) + expf(x.w - Ml);
  }
  for (int i = vecEnd + tid; i < hi; i += NT) sum += expf(lrow[i] - Ml);
  for (int off = 32; off; off >>= 1) sum += __shfl_down(sum, off);
  if ((tid & 63) == 0) wv[tid >> 6] = sum;
  __syncthreads();
  if (tid == 0) {
    float ts = 0.0f;
    for (int w = 0; w < NW; w++) ts += wv[w];
    sSum[b * S + s] = ts;
  }
  __syncthreads();
  for (int j = tid; j < NB; j += NT) {
    int v = lc[j];
    if (v) atomicAdd(&hist[b * NB + j], v);
  }
}

// -------- K2: combine slices -> M, gidx, logZ; hist scan -> edge; mode -----
__global__ __launch_bounds__(NT) void k2(const float* __restrict__ temp,
    const float* __restrict__ topp, const int* __restrict__ topk,
    const int* __restrict__ hist, const float* __restrict__ sMax,
    const int* __restrict__ sArg, const float* __restrict__ sSum,
    float* __restrict__ rowF, int* __restrict__ rowI)
{
  const int b = blockIdx.x, tid = threadIdx.x;
  __shared__ int lc[NB];
  __shared__ int csum[NT];
  for (int j = tid; j < NB; j += NT) lc[j] = hist[b * NB + j];
  __syncthreads();
  int c0 = 0;
  for (int j = tid * (NB / NT); j < (tid + 1) * (NB / NT); j++) c0 += lc[j];
  csum[tid] = c0;
  __syncthreads();
  if (tid == 0) {
    float M = -FLT_MAX; int gi = 0x7fffffff;
    for (int s2 = 0; s2 < S; s2++) {
      float v = sMax[b * S + s2]; int ii = sArg[b * S + s2];
      if (v > M || (v == M && ii < gi)) { M = v; gi = ii; }
    }
    float Z = 0.0f;
    for (int s2 = 0; s2 < S; s2++) Z += sSum[b * S + s2] * expf(sMax[b * S + s2] - M);
    float logZ = logf(Z);
    const int CH = NB / NT;
    int cum = 0; int c = NT - 1;
    for (; c >= 0; c--) {
      if (cum + csum[c] >= TGT) break;
      cum += csum[c];
    }
    if (c < 0) c = 0;
    int bsel = 0, found = -1;
    for (int j = c * CH + CH - 1; j >= c * CH; j--) {
      cum += lc[j];
      if (cum >= TGT) { found = j; break; }
    }
    bsel = (found >= 0) ? found : 0;
    int bc = (bsel >= 2) ? (bsel - 2) : 0;   // 2-bin margin for rank exactness
    float t = temp[b]; float p = topp[b]; int k = topk[b];
    int mode = (t < SEPS) ? 0 : ((k >= 1) ? 1 : 2);
    rowF[b * 16 + 0] = M;
    rowF[b * 16 + 1] = logZ;
    rowF[b * 16 + 2] = XMIN + bc * BINW;     // collect threshold edgeC
    rowF[b * 16 + 3] = (t >= SEPS) ? (M / t) : 0.0f;
    rowF[b * 16 + 4] = t;
    rowF[b * 16 + 5] = p;
    rowI[b * 16 + 0] = gi;
    rowI[b * 16 + 1] = mode;
    rowI[b * 16 + 2] = k;
  }
}

// -------- K3: collect candidates >= edgeC (LDS-staged); mass hist mode2 ----
__global__ __launch_bounds__(NT) void k3(const float* __restrict__ logits,
    int V, int CS, const float* __restrict__ rowF, const int* __restrict__ rowI,
    float* __restrict__ mass, float* __restrict__ candV, int* __restrict__ candI,
    int* __restrict__ cnt1)
{
  const int s = blockIdx.x, b = blockIdx.y, tid = threadIdx.x;
  const float edgeC = rowF[b * 16 + 2];
  const float Ms = rowF[b * 16 + 3];
  const float t = rowF[b * 16 + 4];
  const int mode = rowI[b * 16 + 1];
  const float* lrow = logits + (size_t)b * V;
  const int lo = s * CS, hi = min(V, lo + CS);
  __shared__ int qn; __shared__ int sbase;
  __shared__ float qv[QCAP]; __shared__ int qi[QCAP];
  __shared__ float lm[NB];
  if (tid == 0) qn = 0;
  __syncthreads();
  const int vecEnd = lo + ((hi - lo) & ~3);
  const float4* l4 = reinterpret_cast<const float4*>(lrow);
  #pragma unroll 4
  for (int i4 = (lo >> 2) + tid; i4 < (vecEnd >> 2); i4 += NT) {
    float4 xv = l4[i4];
    float xs[4] = {xv.x, xv.y, xv.z, xv.w};
    int base = i4 << 2;
    #pragma unroll
    for (int q = 0; q < 4; q++) {
      float x = xs[q];
      if (x >= edgeC) {
        int ppos = atomicAdd(&qn, 1);
        if (ppos < QCAP) { qv[ppos] = x; qi[ppos] = base + q; }
      }
    }
  }
  for (int i = vecEnd + tid; i < hi; i += NT) {
    float x = lrow[i];
    if (x >= edgeC) {
      int ppos = atomicAdd(&qn, 1);
      if (ppos < QCAP) { qv[ppos] = x; qi[ppos] = i; }
    }
  }
  __syncthreads();
  int qc = min(qn, QCAP);
  if (tid == 0) sbase = atomicAdd(&cnt1[b], qc);
  __syncthreads();
  for (int j = tid; j < qc; j += NT) {
    int dst = sbase + j;
    if (dst < CAP1) { candV[b * CAP1 + dst] = qv[j]; candI[b * CAP1 + dst] = qi[j]; }
  }
  if (mode == 2) {
    for (int j = tid; j < NB; j += NT) lm[j] = 0.0f;
    __syncthreads();
    #pragma unroll 2
    for (int i4 = (lo >> 2) + tid; i4 < (vecEnd >> 2); i4 += NT) {
      float4 xv = l4[i4];
      atomicAdd(&lm[binOf(xv.x)], expf(xv.x / t - Ms));
      atomicAdd(&lm[binOf(xv.y)], expf(xv.y / t - Ms));
      atomicAdd(&lm[binOf(xv.z)], expf(xv.z / t - Ms));
      atomicAdd(&lm[binOf(xv.w)], expf(xv.w / t - Ms));
    }
    for (int i = vecEnd + tid; i < hi; i += NT)
      atomicAdd(&lm[binOf(lrow[i])], expf(lrow[i] / t - Ms));
    __syncthreads();
    for (int j = tid; j < NB; j += NT)
      if (lm[j] != 0.0f) atomicAdd(&mass[b * NB + j], lm[j]);
  }
}

// ---- K4: sort, top-K out, modes 0/1 sample+rank+final, mode2 mass scan ----
__global__ __launch_bounds__(NT) void k4(const float* __restrict__ logits,
    const float* __restrict__ noise, int V, int K,
    const float* __restrict__ candV, const int* __restrict__ candI,
    const int* __restrict__ cnt1, const float* __restrict__ mass,
    float* __restrict__ rowF, int* __restrict__ rowI,
    float* __restrict__ out, int Bn)
{
  const int b = blockIdx.x, tid = threadIdx.x;
  __shared__ float cv[CAP1]; __shared__ int ci[CAP1];
  __shared__ float sv[CAP1]; __shared__ int si[CAP1];
  __shared__ float ev[CAP1];
  __shared__ float lmass[NB];
  __shared__ float fsum[NT];
  __shared__ float wv[NW]; __shared__ int wi[NW];
  __shared__ int shI[2]; __shared__ float shF[2];
  const int n = min(cnt1[b], CAP1);
  const float M = rowF[b * 16 + 0], logZ = rowF[b * 16 + 1], Ms = rowF[b * 16 + 3];
  const float t = rowF[b * 16 + 4], p = rowF[b * 16 + 5];
  const int mode = rowI[b * 16 + 1], k = rowI[b * 16 + 2], gidx = rowI[b * 16 + 0];

  for (int j = tid; j < n; j += NT) { cv[j] = candV[b * CAP1 + j]; ci[j] = candI[b * CAP1 + j]; }
  __syncthreads();
  for (int c = tid; c < n; c += NT) {
    float v = cv[c]; int id = ci[c]; int r = 0;
    for (int j = 0; j < n; j++) {
      float w = cv[j];
      r += (w > v) || (w == v && ci[j] < id);
    }
    sv[r] = v; si[r] = id;
  }
  __syncthreads();
  float* out_idx = out + Bn;
  float* out_lp  = out + Bn + (size_t)Bn * (K + 1);
  for (int j = tid; j < K && j < n; j += NT) {
    out_idx[(size_t)b * (K + 1) + 1 + j] = (float)si[j];
    out_lp [(size_t)b * (K + 1) + 1 + j] = (sv[j] - M) - logZ;
  }

  if (mode == 2) {
    for (int j = tid; j < NB; j += NT) lmass[j] = mass[b * NB + j];
    __syncthreads();
    const int CH = NB / NT;
    float cs = 0.0f;
    for (int j = tid * CH; j < (tid + 1) * CH; j++) cs += lmass[j];
    fsum[tid] = cs;
    __syncthreads();
    if (tid == 0) {
      float Z2 = 0.0f;
      for (int c = 0; c < NT; c++) Z2 += fsum[c];
      float W = p * Z2;
      float ca = 0.0f; int c = NT - 1;
      for (; c >= 0; c--) {
        if (ca + fsum[c] >= W) break;
        ca += fsum[c];
      }
      if (c < 0) c = 0;
      int Bb = c * CH, found = -1;
      for (int j = c * CH + CH - 1; j >= c * CH; j--) {
        if (ca + lmass[j] >= W) { found = j; break; }
        ca += lmass[j];
      }
      if (found >= 0) Bb = found;
      rowF[b * 16 + 6] = W; rowF[b * 16 + 7] = ca; rowI[b * 16 + 3] = Bb;
    }
    return;
  }

  int smp; float lx;
  if (mode == 0) {
    smp = gidx; lx = M;
  } else {
    const int keff = min(k, n);
    for (int j = tid; j < keff; j += NT) ev[j] = expf(sv[j] / t - Ms);
    __syncthreads();
    if (tid == 0) {
      float Z = 0.0f;
      for (int j = 0; j < keff; j++) Z += ev[j];
      float W = p * Z;
      float cum = 0.0f; int m = 0;
      for (int j = 0; j < keff; j++) {
        if (cum < W) m++; else break;
        cum += ev[j];
      }
      shI[0] = m;
    }
    __syncthreads();
    const int m = shI[0];
    float key = -FLT_MAX; int kid = 0x7fffffff;
    for (int j = tid; j < m; j += NT) {
      float u = noise[(size_t)b * V + si[j]];
      float g = -logf(-logf(u));
      float kk = sv[j] / t + g;
      if (kk > key || (kk == key && si[j] < kid)) { key = kk; kid = si[j]; }
    }
    for (int off = 32; off; off >>= 1) {
      float ov = __shfl_down(key, off);
      int   oi = __shfl_down(kid, off);
      if (ov > key || (ov == key && oi < kid)) { key = ov; kid = oi; }
    }
    if ((tid & 63) == 0) { wv[tid >> 6] = key; wi[tid >> 6] = kid; }
    __syncthreads();
    if (tid == 0) {
      for (int w2 = 1; w2 < NW; w2++)
        if (wv[w2] > key || (wv[w2] == key && wi[w2] < kid)) { key = wv[w2]; kid = wi[w2]; }
      shI[1] = (kid == 0x7fffffff) ? 0 : kid;
    }
    __syncthreads();
    smp = shI[1];
    if (tid == 0) shF[0] = logits[(size_t)b * V + smp];
    __syncthreads();
    lx = shF[0];
  }
  const float tlp = (lx - M) - logZ;
  int rc = 0;
  for (int j = tid; j < n; j += NT) rc += (((sv[j] - M) - logZ) >= tlp) ? 1 : 0;
  for (int off = 32; off; off >>= 1) rc += __shfl_down(rc, off);
  __syncthreads();
  if ((tid & 63) == 0) wi[tid >> 6] = rc;
  __syncthreads();
  if (tid == 0) {
    int rank = 0;
    for (int w2 = 0; w2 < NW; w2++) rank += wi[w2];
    out[b] = (float)smp;
    out_idx[(size_t)b * (K + 1)] = (float)smp;
    out_lp [(size_t)b * (K + 1)] = tlp;
    out[Bn + 2 * (size_t)Bn * (K + 1) + b] = (float)rank;
  }
}

// ---- K5 (mode2): collect bin-Bb elements + above-bin gumbel partials ------
__global__ __launch_bounds__(NT) void k5(const float* __restrict__ logits,
    const float* __restrict__ noise, int V, int CS,
    const float* __restrict__ rowF, const int* __restrict__ rowI,
    float* __restrict__ l2V, int* __restrict__ l2I, int* __restrict__ cnt2,
    float* __restrict__ gbK, int* __restrict__ gbI)
{
  const int s = blockIdx.x, b = blockIdx.y, tid = threadIdx.x;
  if (rowI[b * 16 + 1] != 2) return;
  const int Bb = rowI[b * 16 + 3];
  const float t = rowF[b * 16 + 4];
  const float* lrow = logits + (size_t)b * V;
  const float* nrow = noise + (size_t)b * V;
  const int lo = s * CS, hi = min(V, lo + CS);
  __shared__ int qn; __shared__ int sbase;
  __shared__ float qv[QCAP]; __shared__ int qi[QCAP];
  __shared__ float wv[NW]; __shared__ int wi[NW];
  if (tid == 0) qn = 0;
  __syncthreads();
  float key = -FLT_MAX; int kid = 0x7fffffff;
  for (int i = lo + tid; i < hi; i += NT) {
    float x = lrow[i];
    int bn = binOf(x);
    if (bn > Bb) {
      float g = -logf(-logf(nrow[i]));
      float kk = x / t + g;
      if (kk > key || (kk == key && i < kid)) { key = kk; kid = i; }
    } else if (bn == Bb) {
      int ppos = atomicAdd(&qn, 1);
      if (ppos < QCAP) { qv[ppos] = x; qi[ppos] = i; }
    }
  }
  for (int off = 32; off; off >>= 1) {
    float ov = __shfl_down(key, off);
    int   oi = __shfl_down(kid, off);
    if (ov > key || (ov == key && oi < kid)) { key = ov; kid = oi; }
  }
  if ((tid & 63) == 0) { wv[tid >> 6] = key; wi[tid >> 6] = kid; }
  __syncthreads();
  if (tid == 0) {
    for (int w = 1; w < NW; w++)
      if (wv[w] > key || (wv[w] == key && wi[w] < kid)) { key = wv[w]; kid = wi[w]; }
    gbK[b * S + s] = key; gbI[b * S + s] = kid;
  }
  int qc = min(qn, QCAP);
  if (tid == 0) sbase = atomicAdd(&cnt2[b], qc);
  __syncthreads();
  for (int j = tid; j < qc; j += NT) {
    int dst = sbase + j;
    if (dst < CAP2) { l2V[b * CAP2 + dst] = qv[j]; l2I[b * CAP2 + dst] = qi[j]; }
  }
}

// ---- K6 (mode2): sort bin, exact prefix, sample, bisect xcrit, finalize ---
__global__ __launch_bounds__(NT) void k6(const float* __restrict__ logits,
    const float* __restrict__ noise, int V, int K,
    const float* __restrict__ l2V, const int* __restrict__ l2I,
    const int* __restrict__ cnt2,
    const float* __restrict__ gbK, const int* __restrict__ gbI,
    float* __restrict__ rowF, const int* __restrict__ rowI,
    float* __restrict__ out, int Bn)
{
  const int b = blockIdx.x, tid = threadIdx.x;
  if (rowI[b * 16 + 1] != 2) return;
  __shared__ float cv[CAP2]; __shared__ int ci2[CAP2];
  __shared__ float sv[CAP2]; __shared__ int si2[CAP2];
  __shared__ float ev[CAP2];
  __shared__ float wv[NW]; __shared__ int wi[NW];
  __shared__ int shI[2];
  const int n2 = min(cnt2[b], CAP2);
  const float M = rowF[b * 16 + 0], logZ = rowF[b * 16 + 1], Ms = rowF[b * 16 + 3];
  const float t = rowF[b * 16 + 4];
  const float W = rowF[b * 16 + 6], CAv = rowF[b * 16 + 7];
  for (int j = tid; j < n2; j += NT) { cv[j] = l2V[b * CAP2 + j]; ci2[j] = l2I[b * CAP2 + j]; }
  __syncthreads();
  for (int c = tid; c < n2; c += NT) {
    float v = cv[c]; int id = ci2[c]; int r = 0;
    for (int j = 0; j < n2; j++) {
      float w = cv[j];
      r += (w > v) || (w == v && ci2[j] < id);
    }
    sv[r] = v; si2[r] = id;
  }
  __syncthreads();
  for (int j = tid; j < n2; j += NT) ev[j] = expf(sv[j] / t - Ms);
  __syncthreads();
  if (tid == 0) {
    float cum = CAv; int last = -1;
    for (int j = 0; j < n2; j++) {
      if (cum < W) last = j; else break;
      cum += ev[j];
    }
    shI[0] = last;
  }
  __syncthreads();
  const int last = shI[0];
  float key = -FLT_MAX; int kid = 0x7fffffff;
  for (int j = tid; j <= last; j += NT) {
    float u = noise[(size_t)b * V + si2[j]];
    float g = -logf(-logf(u));
    float kk = sv[j] / t + g;
    if (kk > key || (kk == key && si2[j] < kid)) { key = kk; kid = si2[j]; }
  }
  for (int off = 32; off; off >>= 1) {
    float ov = __shfl_down(key, off);
    int   oi = __shfl_down(kid, off);
    if (ov > key || (ov == key && oi < kid)) { key = ov; kid = oi; }
  }
  if ((tid & 63) == 0) { wv[tid >> 6] = key; wi[tid >> 6] = kid; }
  __syncthreads();
  if (tid == 0) {
    for (int w = 1; w < NW; w++)
      if (wv[w] > key || (wv[w] == key && wi[w] < kid)) { key = wv[w]; kid = wi[w]; }
    for (int s2 = 0; s2 < S; s2++) {
      float v = gbK[b * S + s2]; int ii = gbI[b * S + s2];
      if (v > key || (v == key && ii < kid)) { key = v; kid = ii; }
    }
    int smp = (kid == 0x7fffffff) ? 0 : kid;
    float lx = logits[(size_t)b * V + smp];
    float tlp = (lx - M) - logZ;
    unsigned loK = f2k(-3.0e38f);
    unsigned hiK = f2k(lx);
    while (hiK - loK > 1u) {
      unsigned mid = loK + ((hiK - loK) >> 1);
      float xm = k2f(mid);
      if (((xm - M) - logZ) >= tlp) hiK = mid; else loK = mid;
    }
    rowF[b * 16 + 9] = k2f(hiK);   // xcrit
    out[b] = (float)smp;
    out[Bn + (size_t)b * (K + 1)] = (float)smp;
    out[Bn + (size_t)Bn * (K + 1) + (size_t)b * (K + 1)] = tlp;
    out[Bn + 2 * (size_t)Bn * (K + 1) + b] = 0.0f;
  }
}

// ---- K7 (mode2): rank = count(x >= xcrit) per slice -> atomic add ---------
__global__ __launch_bounds__(NT) void k7(const float* __restrict__ logits,
    int V, int CS, const float* __restrict__ rowF, const int* __restrict__ rowI,
    float* __restrict__ out, int Bn, int K)
{
  const int s = blockIdx.x, b = blockIdx.y, tid = threadIdx.x;
  if (rowI[b * 16 + 1] != 2) return;
  const float xcrit = rowF[b * 16 + 9];
  const float* lrow = logits + (size_t)b * V;
  const int lo = s * CS, hi = min(V, lo + CS);
  __shared__ int wiv[NW];
  int rc = 0;
  const int vecEnd = lo + ((hi - lo) & ~3);
  const float4* l4 = reinterpret_cast<const float4*>(lrow);
  #pragma unroll 4
  for (int i4 = (lo >> 2) + tid; i4 < (vecEnd >> 2); i4 += NT) {
    float4 x = l4[i4];
    rc += (x.x >= xcrit) + (x.y >= xcrit) + (x.z >= xcrit) + (x.w >= xcrit);
  }
  for (int i = vecEnd + tid; i < hi; i += NT) rc += (lrow[i] >= xcrit);
  for (int off = 32; off; off >>= 1) rc += __shfl_down(rc, off);
  if ((tid & 63) == 0) wiv[tid >> 6] = rc;
  __syncthreads();
  if (tid == 0) {
    int tot = 0;
    for (int w = 0; w < NW; w++) tot += wiv[w];
    atomicAdd(&out[Bn + 2 * (size_t)Bn * (K + 1) + b], (float)tot);
  }
}

extern "C" void kernel_launch(void* const* d_in, const int* in_sizes, int n_in,
                              void* d_out, int out_size, void* d_ws, size_t ws_size,
                              hipStream_t stream) {
  const float* logits = (const float*)d_in[0];
  const float* temp   = (const float*)d_in[1];
  const float* topp   = (const float*)d_in[2];
  const float* noise  = (const float*)d_in[3];
  const int*   topk   = (const int*)d_in[4];
  const int Bn = in_sizes[1];                         // 128
  const int V  = in_sizes[0] / Bn;                    // 128256
  const int K  = (out_size - 2 * Bn) / (2 * Bn) - 1;  // 20
  const int CS = (((V + S - 1) / S) + 3) & ~3;

  char* w = (char*)d_ws;
  int*   hist  = (int*)w;    w += (size_t)Bn * NB * 4;
  float* mass  = (float*)w;  w += (size_t)Bn * NB * 4;
  int*   cnt1  = (int*)w;    w += (size_t)Bn * 4;
  int*   cnt2  = (int*)w;    w += (size_t)Bn * 4;
  size_t zeroBytes = (size_t)(w - (char*)d_ws);
  float* sMax  = (float*)w;  w += (size_t)Bn * S * 4;
  int*   sArg  = (int*)w;    w += (size_t)Bn * S * 4;
  float* sSum  = (float*)w;  w += (size_t)Bn * S * 4;
  float* gbK   = (float*)w;  w += (size_t)Bn * S * 4;
  int*   gbI   = (int*)w;    w += (size_t)Bn * S * 4;
  float* candV = (float*)w;  w += (size_t)Bn * CAP1 * 4;
  int*   candI = (int*)w;    w += (size_t)Bn * CAP1 * 4;
  float* l2V   = (float*)w;  w += (size_t)Bn * CAP2 * 4;
  int*   l2I   = (int*)w;    w += (size_t)Bn * CAP2 * 4;
  float* rowF  = (float*)w;  w += (size_t)Bn * 16 * 4;
  int*   rowI  = (int*)w;    w += (size_t)Bn * 16 * 4;

  hipMemsetAsync(d_ws, 0, zeroBytes, stream);

  dim3 gs(S, Bn);
  k1<<<gs, NT, 0, stream>>>(logits, V, CS, hist, sMax, sArg, sSum);
  k2<<<Bn, NT, 0, stream>>>(temp, topp, topk, hist, sMax, sArg, sSum, rowF, rowI);
  k3<<<gs, NT, 0, stream>>>(logits, V, CS, rowF, rowI, mass, candV, candI, cnt1);
  k4<<<Bn, NT, 0, stream>>>(logits, noise, V, K, candV, candI, cnt1, mass, rowF, rowI,
                            (float*)d_out, Bn);
  k5<<<gs, NT, 0, stream>>>(logits, noise, V, CS, rowF, rowI, l2V, l2I, cnt2, gbK, gbI);
  k6<<<Bn, NT, 0, stream>>>(logits, noise, V, K, l2V, l2I, cnt2, gbK, gbI, rowF, rowI,
                            (float*)d_out, Bn);
  k7<<<gs, NT, 0, stream>>>(logits, V, CS, rowF, rowI, (float*)d_out, Bn, K);
}